// Round 4
// baseline (1750.855 us; speedup 1.0000x reference)
//
#include <hip/hip_runtime.h>
#include <math.h>

// Problem constants
#define BB    4096   // batch
#define LL    30     // seq len
#define WW    5      // window
#define CC    40     // conv channels
#define HH    128    // lstm units
#define TT    3      // crf tags
#define KA    328    // 200 (features) + 128 (h)
#define NB    32     // batch rows per LSTM block

// Workspace layout (in floats)
#define WS_P    0                         // P'[3][30][40] conv collapsed + bn1 folded
#define WS_BC   3600                      // biasC[40]
#define WS_BG   3648                      // biasG[2][512]
#define WS_WFC  4672                      // Wfc[2][3][128]  (fc folded with bn2)
#define WS_EB   5440                      // ebias[3]
#define WS_WT   5504                      // Wt[2][328][128][4]  [k][unit][gate i,f,g,o]
#define WS_EMIS (5504 + 2*328*512)        // emis[2][B][L][3] partial emissions

__device__ __forceinline__ float sigm(float x) {
    return __builtin_amdgcn_rcpf(1.0f + __expf(-x));
}
__device__ __forceinline__ float tanh_fast(float x) {
    return 2.0f * __builtin_amdgcn_rcpf(1.0f + __expf(-2.0f * x)) - 1.0f;
}

// ---------------------------------------------------------------------------
// Kernel 1: fold BN1 into conv tables, repack LSTM weights, fold BN2 into FC
// ---------------------------------------------------------------------------
__global__ void prep_kernel(const float* __restrict__ emb, const float* __restrict__ conv_w,
                            const float* __restrict__ conv_b,
                            const float* __restrict__ bn1_g, const float* __restrict__ bn1_b,
                            const float* __restrict__ bn1_m, const float* __restrict__ bn1_v,
                            const float* __restrict__ w_ih_f, const float* __restrict__ w_hh_f,
                            const float* __restrict__ b_f,
                            const float* __restrict__ w_ih_b, const float* __restrict__ w_hh_b,
                            const float* __restrict__ b_b,
                            const float* __restrict__ bn2_g, const float* __restrict__ bn2_b,
                            const float* __restrict__ bn2_m, const float* __restrict__ bn2_v,
                            const float* __restrict__ fc_w, const float* __restrict__ fc_b,
                            float* __restrict__ ws)
{
    const int gid = blockIdx.x * blockDim.x + threadIdx.x;
    const int gsz = gridDim.x * blockDim.x;

    // P'[k][a][c] = s1[c] * sum_e emb[a,e] * conv_w[c,e,k]
    for (int idx = gid; idx < 3600; idx += gsz) {
        int k = idx / 1200, rem = idx % 1200, a = rem / 40, c = rem % 40;
        float s1 = bn1_g[c] / sqrtf(bn1_v[c] + 1e-5f);
        float acc = 0.f;
        for (int e = 0; e < 128; ++e)
            acc += emb[a * 128 + e] * conv_w[(c * 128 + e) * 3 + k];
        ws[WS_P + idx] = acc * s1;
    }
    for (int c = gid; c < CC; c += gsz) {
        float s1 = bn1_g[c] / sqrtf(bn1_v[c] + 1e-5f);
        ws[WS_BC + c] = (conv_b[c] - bn1_m[c]) * s1 + bn1_b[c];
    }
    for (int i = gid; i < 1024; i += gsz) {
        int d = i >> 9, g = i & 511;
        ws[WS_BG + i] = d ? b_b[g] : b_f[g];
    }
    for (int i = gid; i < 768; i += gsz) {
        int d = i / 384, r = i % 384, t = r / 128, u = r % 128;
        int j = d * 128 + u;
        float s2 = bn2_g[j] / sqrtf(bn2_v[j] + 1e-5f);
        ws[WS_WFC + i] = fc_w[t * 256 + j] * s2;
    }
    for (int t = gid; t < TT; t += gsz) {
        float acc = fc_b[t];
        for (int j = 0; j < 256; ++j) {
            float s2 = bn2_g[j] / sqrtf(bn2_v[j] + 1e-5f);
            acc += fc_w[t * 256 + j] * (bn2_b[j] - bn2_m[j] * s2);
        }
        ws[WS_EB + t] = acc;
    }
    // Wt[d][k][u][g]: gate-quad contiguous per (k,unit) -> one dwordx4 per thread.
    // g in {0:i, 1:f, 2:g, 3:o} -> source row = g*128+u of the [512, *] matrices.
    for (int i = gid; i < 2 * KA * 512; i += gsz) {
        int d = i / (KA * 512), r = i % (KA * 512);
        int k = r / 512, j = r % 512, u = j >> 2, g = j & 3;
        int row = g * 128 + u;
        const float* wih = d ? w_ih_b : w_ih_f;
        const float* whh = d ? w_hh_b : w_hh_f;
        ws[WS_WT + i] = (k < 200) ? wih[row * 200 + k] : whh[row * 128 + (k - 200)];
    }
}

// ---------------------------------------------------------------------------
// Kernel 2: fused features + BiLSTM + partial emissions.
// 256 blocks = 2 dirs x 128 tiles of NB=32 rows; 256 threads = 4 waves =
// (2 row-halves of 16) x (2 unit-halves of 64). Each lane owns ONE unit
// (all 4 gates) x 16 rows: acc[16][4]. Weights stream from L2 via plain
// global dwordx4 (layout Wt[k][u][4]) — no LDS staging, no K-loop barriers.
// A (features+h) lives in LDS; A-reads are wave-uniform b128 broadcasts.
// ---------------------------------------------------------------------------
__global__ __launch_bounds__(256, 1)
void lstm_kernel(const int* __restrict__ x, float* __restrict__ ws)
{
    __shared__ float A[NB][336];         // [features(200) | h(128) | pad]
    __shared__ float Pp_s[3600];
    __shared__ float Wfc_s[384];
    __shared__ float biasC_s[40];

    const int tid = threadIdx.x;
    const int d   = blockIdx.x & 1;
    const int b0  = (blockIdx.x >> 1) * NB;

    const float4* __restrict__ Wg = (const float4*)(ws + WS_WT + d * (KA * 512));
    float* emis = ws + WS_EMIS + d * (BB * LL * TT);

    for (int i = tid; i < 3600; i += 256) Pp_s[i] = ws[WS_P + i];
    for (int i = tid; i < 384;  i += 256) Wfc_s[i] = ws[WS_WFC + d * 384 + i];
    for (int i = tid; i < 40;   i += 256) biasC_s[i] = ws[WS_BC + i];
    for (int i = tid; i < NB * HH; i += 256) A[i >> 7][200 + (i & 127)] = 0.f;

    const int lane = tid & 63;
    const int wv   = tid >> 6;
    const int uh   = wv & 1;            // unit half
    const int rb   = (wv >> 1) * 16;    // row base
    const int u    = uh * 64 + lane;    // this thread's unit

    // gate biases for unit u (i,f,g,o)
    const float* bgp = ws + WS_BG + d * 512;
    const float bI = bgp[u], bF = bgp[128 + u], bG = bgp[256 + u], bO = bgp[384 + u];

    float acc[16][4];
    float cstv[16];
    #pragma unroll
    for (int r = 0; r < 16; ++r) cstv[r] = 0.f;

    __syncthreads();

    for (int step = 0; step < LL; ++step) {
        const int l = d ? (LL - 1 - step) : step;

        // ---- features: conv(table lookups) + bn1 + relu + maxpool -> A[:, :200]
        for (int p = tid; p < NB * CC; p += 256) {
            int bb = p / CC, c = p % CC;
            const int* tok = x + (((b0 + bb) * LL) + l) * WW;
            int t0 = tok[0], t1 = tok[1], t2 = tok[2], t3 = tok[3], t4 = tok[4];
            float bc = biasC_s[c];
            float a0 = bc + Pp_s[(30 + t0) * 40 + c] + Pp_s[(60 + t1) * 40 + c];
            float a1 = bc + Pp_s[t0 * 40 + c] + Pp_s[(30 + t1) * 40 + c] + Pp_s[(60 + t2) * 40 + c];
            float a2 = bc + Pp_s[t1 * 40 + c] + Pp_s[(30 + t2) * 40 + c] + Pp_s[(60 + t3) * 40 + c];
            float a3 = bc + Pp_s[t2 * 40 + c] + Pp_s[(30 + t3) * 40 + c] + Pp_s[(60 + t4) * 40 + c];
            float a4 = bc + Pp_s[t3 * 40 + c] + Pp_s[(30 + t4) * 40 + c];
            a0 = fmaxf(a0, 0.f); a1 = fmaxf(a1, 0.f); a2 = fmaxf(a2, 0.f);
            a3 = fmaxf(a3, 0.f); a4 = fmaxf(a4, 0.f);
            float* Af = &A[bb][c * 5];
            Af[0] = fmaxf(a0, a1);
            Af[1] = fmaxf(fmaxf(a0, a1), a2);
            Af[2] = fmaxf(fmaxf(a1, a2), a3);
            Af[3] = fmaxf(fmaxf(a2, a3), a4);
            Af[4] = fmaxf(a3, a4);
        }
        __syncthreads();   // features visible

        // ---- GEMM: acc[r][g] = sum_k A[rb+r][k] * Wt[k][u][g], k = 0..327 ----
        #pragma unroll
        for (int r = 0; r < 16; ++r) {
            acc[r][0] = 0.f; acc[r][1] = 0.f; acc[r][2] = 0.f; acc[r][3] = 0.f;
        }

        float4 wcur[8], wnxt[8];
        #pragma unroll
        for (int i = 0; i < 8; ++i) wcur[i] = Wg[i * 128 + u];

        for (int kb = 0; kb < 41; ++kb) {           // 41 * 8 = 328 exactly
            if (kb < 40) {
                #pragma unroll
                for (int i = 0; i < 8; ++i)
                    wnxt[i] = Wg[((kb + 1) * 8 + i) * 128 + u];
            }
            const int k0 = kb * 8;
            #pragma unroll
            for (int r = 0; r < 16; ++r) {
                float4 aA = *(const float4*)&A[rb + r][k0];
                float4 aB = *(const float4*)&A[rb + r][k0 + 4];
                float av[8] = {aA.x, aA.y, aA.z, aA.w, aB.x, aB.y, aB.z, aB.w};
                #pragma unroll
                for (int kk = 0; kk < 8; ++kk) {
                    acc[r][0] = fmaf(av[kk], wcur[kk].x, acc[r][0]);
                    acc[r][1] = fmaf(av[kk], wcur[kk].y, acc[r][1]);
                    acc[r][2] = fmaf(av[kk], wcur[kk].z, acc[r][2]);
                    acc[r][3] = fmaf(av[kk], wcur[kk].w, acc[r][3]);
                }
            }
            #pragma unroll
            for (int i = 0; i < 8; ++i) wcur[i] = wnxt[i];
        }

        __syncthreads();   // all GEMM reads of h done before h overwrite

        // ---- gates (thread owns i,f,g,o of its unit) -> h into A[:,200+u] ----
        #pragma unroll
        for (int r = 0; r < 16; ++r) {
            float zi = acc[r][0] + bI;
            float zf = acc[r][1] + bF;
            float zg = acc[r][2] + bG;
            float zo = acc[r][3] + bO;
            float cn = sigm(zf) * cstv[r] + sigm(zi) * tanh_fast(zg);
            cstv[r] = cn;
            A[rb + r][200 + u] = sigm(zo) * tanh_fast(cn);
        }
        __syncthreads();   // h visible to emission readers + next step's GEMM

        // ---- partial emissions: 32 rows x 3 tags, split in 2 segments ----
        if (tid < 192) {
            int bb = tid / 6, r6 = tid % 6, t = r6 >> 1, seg = r6 & 1;
            const float* hv = &A[bb][200 + seg * 64];
            const float* wfc = &Wfc_s[t * 128 + seg * 64];
            float s = 0.f;
            #pragma unroll
            for (int i = 0; i < 16; ++i) {
                float4 ha = *(const float4*)(hv + i * 4);
                float4 wa = *(const float4*)(wfc + i * 4);
                s += ha.x * wa.x + ha.y * wa.y + ha.z * wa.z + ha.w * wa.w;
            }
            s += __shfl_xor(s, 1);
            if (seg == 0)
                emis[(((b0 + bb) * LL) + l) * TT + t] = s;
        }
        // next features phase writes A[:, :200] only; emission reads h region —
        // disjoint, no barrier needed here.
    }
}

// ---------------------------------------------------------------------------
// Kernel 3: Viterbi decode. One thread per batch row.
// ---------------------------------------------------------------------------
__global__ void viterbi_kernel(const int* __restrict__ x, const float* __restrict__ ws,
                               const float* __restrict__ trans,
                               const float* __restrict__ start_t,
                               const float* __restrict__ end_t,
                               float* __restrict__ out)
{
    int b = blockIdx.x * blockDim.x + threadIdx.x;
    if (b >= BB) return;
    const float* eF = ws + WS_EMIS;
    const float* eB = ws + WS_EMIS + BB * LL * TT;
    const float eb0 = ws[WS_EB + 0], eb1 = ws[WS_EB + 1], eb2 = ws[WS_EB + 2];
    float tr[9];
    #pragma unroll
    for (int i = 0; i < 9; ++i) tr[i] = trans[i];

    int base = b * LL * TT;
    float s0 = start_t[0] + eF[base + 0] + eB[base + 0] + eb0;
    float s1 = start_t[1] + eF[base + 1] + eB[base + 1] + eb1;
    float s2 = start_t[2] + eF[base + 2] + eB[base + 2] + eb2;

    unsigned hist[LL - 1];
    unsigned maskbits = 0;

    #pragma unroll
    for (int l = 1; l < LL; ++l) {
        bool m = x[(b * LL + l) * WW + 2] > 0;
        if (m) maskbits |= (1u << l);
        int idx = base + l * TT;
        float e0 = eF[idx + 0] + eB[idx + 0] + eb0;
        float e1 = eF[idx + 1] + eB[idx + 1] + eb1;
        float e2 = eF[idx + 2] + eB[idx + 2] + eb2;

        float ns[3]; int pt[3];
        #pragma unroll
        for (int nt = 0; nt < 3; ++nt) {
            float c0 = s0 + tr[0 * 3 + nt];
            float c1 = s1 + tr[1 * 3 + nt];
            float c2 = s2 + tr[2 * 3 + nt];
            int p = 0; float bc = c0;
            if (c1 > bc) { bc = c1; p = 1; }   // strict '>': first-index argmax
            if (c2 > bc) { bc = c2; p = 2; }
            ns[nt] = bc; pt[nt] = p;
        }
        ns[0] += e0; ns[1] += e1; ns[2] += e2;
        hist[l - 1] = (unsigned)pt[0] | ((unsigned)pt[1] << 2) | ((unsigned)pt[2] << 4);
        if (m) { s0 = ns[0]; s1 = ns[1]; s2 = ns[2]; }
    }
    s0 += end_t[0]; s1 += end_t[1]; s2 += end_t[2];
    float best = s0; int last = 0;
    if (s1 > best) { best = s1; last = 1; }
    if (s2 > best) { best = s2; last = 2; }

    out[b] = best;
    float* tags = out + BB + b * LL;
    int tag = last;
    tags[LL - 1] = (float)last;
    #pragma unroll
    for (int l = LL - 1; l >= 1; --l) {
        int prev = (int)((hist[l - 1] >> (2 * tag)) & 3u);
        if (maskbits & (1u << l)) tag = prev;
        tags[l - 1] = (float)tag;
    }
}

// ---------------------------------------------------------------------------
extern "C" void kernel_launch(void* const* d_in, const int* in_sizes, int n_in,
                              void* d_out, int out_size, void* d_ws, size_t ws_size,
                              hipStream_t stream)
{
    const int*   x      = (const int*)  d_in[0];
    const float* emb    = (const float*)d_in[1];
    const float* conv_w = (const float*)d_in[2];
    const float* conv_b = (const float*)d_in[3];
    const float* bn1_g  = (const float*)d_in[4];
    const float* bn1_b  = (const float*)d_in[5];
    const float* bn1_m  = (const float*)d_in[6];
    const float* bn1_v  = (const float*)d_in[7];
    const float* w_ih_f = (const float*)d_in[8];
    const float* w_hh_f = (const float*)d_in[9];
    const float* b_f    = (const float*)d_in[10];
    const float* w_ih_b = (const float*)d_in[11];
    const float* w_hh_b = (const float*)d_in[12];
    const float* b_b    = (const float*)d_in[13];
    const float* bn2_g  = (const float*)d_in[14];
    const float* bn2_b  = (const float*)d_in[15];
    const float* bn2_m  = (const float*)d_in[16];
    const float* bn2_v  = (const float*)d_in[17];
    const float* fc_w   = (const float*)d_in[18];
    const float* fc_b   = (const float*)d_in[19];
    const float* trans  = (const float*)d_in[20];
    const float* start_t= (const float*)d_in[21];
    const float* end_t  = (const float*)d_in[22];

    float* ws  = (float*)d_ws;
    float* out = (float*)d_out;

    prep_kernel<<<256, 256, 0, stream>>>(emb, conv_w, conv_b,
                                         bn1_g, bn1_b, bn1_m, bn1_v,
                                         w_ih_f, w_hh_f, b_f,
                                         w_ih_b, w_hh_b, b_b,
                                         bn2_g, bn2_b, bn2_m, bn2_v,
                                         fc_w, fc_b, ws);
    lstm_kernel<<<256, 256, 0, stream>>>(x, ws);
    viterbi_kernel<<<16, 256, 0, stream>>>(x, ws, trans, start_t, end_t, out);
}

// Round 5
// 1267.007 us; speedup vs baseline: 1.3819x; 1.3819x over previous
//
#include <hip/hip_runtime.h>
#include <math.h>

// Problem constants
#define BB    4096   // batch
#define LL    30     // seq len
#define WW    5      // window
#define CC    40     // conv channels
#define HH    128    // lstm units
#define TT    3      // crf tags
#define KA    328    // 200 (features) + 128 (h)
#define NB    32     // batch rows per LSTM block

// Workspace layout (in floats)
#define WS_P    0                         // P'[3][30][40] conv collapsed + bn1 folded
#define WS_BC   3600                      // biasC[40]
#define WS_BG   3648                      // biasG[2][512]
#define WS_WFC  4672                      // Wfc[2][3][128]  (fc folded with bn2)
#define WS_EB   5440                      // ebias[3]
#define WS_WT   5504                      // Wt[2][328][128][4]  [k][unit][gate i,f,g,o]
#define WS_EMIS (5504 + 2*328*512)        // emis[2][B][L][3] partial emissions

__device__ __forceinline__ float sigm(float x) {
    return __builtin_amdgcn_rcpf(1.0f + __expf(-x));
}
__device__ __forceinline__ float tanh_fast(float x) {
    return 2.0f * __builtin_amdgcn_rcpf(1.0f + __expf(-2.0f * x)) - 1.0f;
}

// ---------------------------------------------------------------------------
// Kernel 1: fold BN1 into conv tables, repack LSTM weights, fold BN2 into FC
// ---------------------------------------------------------------------------
__global__ void prep_kernel(const float* __restrict__ emb, const float* __restrict__ conv_w,
                            const float* __restrict__ conv_b,
                            const float* __restrict__ bn1_g, const float* __restrict__ bn1_b,
                            const float* __restrict__ bn1_m, const float* __restrict__ bn1_v,
                            const float* __restrict__ w_ih_f, const float* __restrict__ w_hh_f,
                            const float* __restrict__ b_f,
                            const float* __restrict__ w_ih_b, const float* __restrict__ w_hh_b,
                            const float* __restrict__ b_b,
                            const float* __restrict__ bn2_g, const float* __restrict__ bn2_b,
                            const float* __restrict__ bn2_m, const float* __restrict__ bn2_v,
                            const float* __restrict__ fc_w, const float* __restrict__ fc_b,
                            float* __restrict__ ws)
{
    const int gid = blockIdx.x * blockDim.x + threadIdx.x;
    const int gsz = gridDim.x * blockDim.x;

    // P'[k][a][c] = s1[c] * sum_e emb[a,e] * conv_w[c,e,k]
    for (int idx = gid; idx < 3600; idx += gsz) {
        int k = idx / 1200, rem = idx % 1200, a = rem / 40, c = rem % 40;
        float s1 = bn1_g[c] / sqrtf(bn1_v[c] + 1e-5f);
        float acc = 0.f;
        for (int e = 0; e < 128; ++e)
            acc += emb[a * 128 + e] * conv_w[(c * 128 + e) * 3 + k];
        ws[WS_P + idx] = acc * s1;
    }
    for (int c = gid; c < CC; c += gsz) {
        float s1 = bn1_g[c] / sqrtf(bn1_v[c] + 1e-5f);
        ws[WS_BC + c] = (conv_b[c] - bn1_m[c]) * s1 + bn1_b[c];
    }
    for (int i = gid; i < 1024; i += gsz) {
        int d = i >> 9, g = i & 511;
        ws[WS_BG + i] = d ? b_b[g] : b_f[g];
    }
    for (int i = gid; i < 768; i += gsz) {
        int d = i / 384, r = i % 384, t = r / 128, u = r % 128;
        int j = d * 128 + u;
        float s2 = bn2_g[j] / sqrtf(bn2_v[j] + 1e-5f);
        ws[WS_WFC + i] = fc_w[t * 256 + j] * s2;
    }
    for (int t = gid; t < TT; t += gsz) {
        float acc = fc_b[t];
        for (int j = 0; j < 256; ++j) {
            float s2 = bn2_g[j] / sqrtf(bn2_v[j] + 1e-5f);
            acc += fc_w[t * 256 + j] * (bn2_b[j] - bn2_m[j] * s2);
        }
        ws[WS_EB + t] = acc;
    }
    // Wt[d][k][u][g]: gate-quad contiguous per (k,unit) -> one dwordx4 per thread.
    for (int i = gid; i < 2 * KA * 512; i += gsz) {
        int d = i / (KA * 512), r = i % (KA * 512);
        int k = r / 512, j = r % 512, u = j >> 2, g = j & 3;
        int row = g * 128 + u;
        const float* wih = d ? w_ih_b : w_ih_f;
        const float* whh = d ? w_hh_b : w_hh_f;
        ws[WS_WT + i] = (k < 200) ? wih[row * 200 + k] : whh[row * 128 + (k - 200)];
    }
}

// ---------------------------------------------------------------------------
// Kernel 2: fused features + BiLSTM + partial emissions.
// 256 blocks = 2 dirs x 128 tiles of NB=32 rows; 512 threads = 8 waves =
// (4 row-quarters of 8) x (2 unit-halves of 64) -> 2 waves/SIMD for latency
// hiding (R4's 1 wave/SIMD left ~2.5Kcyc/kb of exposed vmcnt/lgkm stalls).
// Each lane owns ONE unit (4 gates) x 8 rows: acc[8][4]. Weights stream from
// L2 via global dwordx4 (Wt[k][u][4]); A-reads are wave-uniform b128
// broadcasts from LDS; no K-loop barriers.
// ---------------------------------------------------------------------------
__global__ __launch_bounds__(512, 1)
void lstm_kernel(const int* __restrict__ x, float* __restrict__ ws)
{
    __shared__ float A[NB][336];         // [features(200) | h(128) | pad]
    __shared__ float Pp_s[3600];
    __shared__ float Wfc_s[384];
    __shared__ float biasC_s[40];

    const int tid = threadIdx.x;
    const int d   = blockIdx.x & 1;
    const int b0  = (blockIdx.x >> 1) * NB;

    const float4* __restrict__ Wg = (const float4*)(ws + WS_WT + d * (KA * 512));
    float* emis = ws + WS_EMIS + d * (BB * LL * TT);

    for (int i = tid; i < 3600; i += 512) Pp_s[i] = ws[WS_P + i];
    for (int i = tid; i < 384;  i += 512) Wfc_s[i] = ws[WS_WFC + d * 384 + i];
    for (int i = tid; i < 40;   i += 512) biasC_s[i] = ws[WS_BC + i];
    for (int i = tid; i < NB * HH; i += 512) A[i >> 7][200 + (i & 127)] = 0.f;

    const int lane = tid & 63;
    const int wv   = tid >> 6;          // 0..7
    const int uh   = wv & 1;            // unit half
    const int rb   = (wv >> 1) * 8;     // row base (4 quarters of 8)
    const int u    = uh * 64 + lane;    // this thread's unit

    // gate biases for unit u (i,f,g,o)
    const float* bgp = ws + WS_BG + d * 512;
    const float bI = bgp[u], bF = bgp[128 + u], bG = bgp[256 + u], bO = bgp[384 + u];

    float acc[8][4];
    float cstv[8];
    #pragma unroll
    for (int r = 0; r < 8; ++r) cstv[r] = 0.f;

    __syncthreads();

    for (int step = 0; step < LL; ++step) {
        const int l = d ? (LL - 1 - step) : step;

        // ---- features: conv(table lookups) + bn1 + relu + maxpool -> A[:, :200]
        for (int p = tid; p < NB * CC; p += 512) {
            int bb = p / CC, c = p % CC;
            const int* tok = x + (((b0 + bb) * LL) + l) * WW;
            int t0 = tok[0], t1 = tok[1], t2 = tok[2], t3 = tok[3], t4 = tok[4];
            float bc = biasC_s[c];
            float a0 = bc + Pp_s[(30 + t0) * 40 + c] + Pp_s[(60 + t1) * 40 + c];
            float a1 = bc + Pp_s[t0 * 40 + c] + Pp_s[(30 + t1) * 40 + c] + Pp_s[(60 + t2) * 40 + c];
            float a2 = bc + Pp_s[t1 * 40 + c] + Pp_s[(30 + t2) * 40 + c] + Pp_s[(60 + t3) * 40 + c];
            float a3 = bc + Pp_s[t2 * 40 + c] + Pp_s[(30 + t3) * 40 + c] + Pp_s[(60 + t4) * 40 + c];
            float a4 = bc + Pp_s[t3 * 40 + c] + Pp_s[(30 + t4) * 40 + c];
            a0 = fmaxf(a0, 0.f); a1 = fmaxf(a1, 0.f); a2 = fmaxf(a2, 0.f);
            a3 = fmaxf(a3, 0.f); a4 = fmaxf(a4, 0.f);
            float* Af = &A[bb][c * 5];
            Af[0] = fmaxf(a0, a1);
            Af[1] = fmaxf(fmaxf(a0, a1), a2);
            Af[2] = fmaxf(fmaxf(a1, a2), a3);
            Af[3] = fmaxf(fmaxf(a2, a3), a4);
            Af[4] = fmaxf(a3, a4);
        }
        __syncthreads();   // features visible

        // ---- GEMM: acc[r][g] = sum_k A[rb+r][k] * Wt[k][u][g], k = 0..327 ----
        #pragma unroll
        for (int r = 0; r < 8; ++r) {
            acc[r][0] = 0.f; acc[r][1] = 0.f; acc[r][2] = 0.f; acc[r][3] = 0.f;
        }

        float4 wcur[8], wnxt[8];
        #pragma unroll
        for (int i = 0; i < 8; ++i) wcur[i] = Wg[i * 128 + u];

        for (int kb = 0; kb < 41; ++kb) {           // 41 * 8 = 328 exactly
            if (kb < 40) {
                #pragma unroll
                for (int i = 0; i < 8; ++i)
                    wnxt[i] = Wg[((kb + 1) * 8 + i) * 128 + u];
            }
            const int k0 = kb * 8;
            #pragma unroll
            for (int r = 0; r < 8; ++r) {
                float4 aA = *(const float4*)&A[rb + r][k0];
                float4 aB = *(const float4*)&A[rb + r][k0 + 4];
                float av[8] = {aA.x, aA.y, aA.z, aA.w, aB.x, aB.y, aB.z, aB.w};
                #pragma unroll
                for (int kk = 0; kk < 8; ++kk) {
                    acc[r][0] = fmaf(av[kk], wcur[kk].x, acc[r][0]);
                    acc[r][1] = fmaf(av[kk], wcur[kk].y, acc[r][1]);
                    acc[r][2] = fmaf(av[kk], wcur[kk].z, acc[r][2]);
                    acc[r][3] = fmaf(av[kk], wcur[kk].w, acc[r][3]);
                }
            }
            #pragma unroll
            for (int i = 0; i < 8; ++i) wcur[i] = wnxt[i];
        }

        __syncthreads();   // all GEMM reads of h done before h overwrite

        // ---- gates (thread owns i,f,g,o of its unit) -> h into A[:,200+u] ----
        #pragma unroll
        for (int r = 0; r < 8; ++r) {
            float zi = acc[r][0] + bI;
            float zf = acc[r][1] + bF;
            float zg = acc[r][2] + bG;
            float zo = acc[r][3] + bO;
            float cn = sigm(zf) * cstv[r] + sigm(zi) * tanh_fast(zg);
            cstv[r] = cn;
            A[rb + r][200 + u] = sigm(zo) * tanh_fast(cn);
        }
        __syncthreads();   // h visible to emission readers + next step's GEMM

        // ---- partial emissions: 32 rows x 3 tags, split in 2 segments ----
        if (tid < 192) {
            int bb = tid / 6, r6 = tid % 6, t = r6 >> 1, seg = r6 & 1;
            const float* hv = &A[bb][200 + seg * 64];
            const float* wfc = &Wfc_s[t * 128 + seg * 64];
            float s = 0.f;
            #pragma unroll
            for (int i = 0; i < 16; ++i) {
                float4 ha = *(const float4*)(hv + i * 4);
                float4 wa = *(const float4*)(wfc + i * 4);
                s += ha.x * wa.x + ha.y * wa.y + ha.z * wa.z + ha.w * wa.w;
            }
            s += __shfl_xor(s, 1);
            if (seg == 0)
                emis[(((b0 + bb) * LL) + l) * TT + t] = s;
        }
        // next features phase writes A[:, :200] only; emission reads h region —
        // disjoint, no barrier needed here.
    }
}

// ---------------------------------------------------------------------------
// Kernel 3: Viterbi decode. One thread per batch row.
// ---------------------------------------------------------------------------
__global__ void viterbi_kernel(const int* __restrict__ x, const float* __restrict__ ws,
                               const float* __restrict__ trans,
                               const float* __restrict__ start_t,
                               const float* __restrict__ end_t,
                               float* __restrict__ out)
{
    int b = blockIdx.x * blockDim.x + threadIdx.x;
    if (b >= BB) return;
    const float* eF = ws + WS_EMIS;
    const float* eB = ws + WS_EMIS + BB * LL * TT;
    const float eb0 = ws[WS_EB + 0], eb1 = ws[WS_EB + 1], eb2 = ws[WS_EB + 2];
    float tr[9];
    #pragma unroll
    for (int i = 0; i < 9; ++i) tr[i] = trans[i];

    int base = b * LL * TT;
    float s0 = start_t[0] + eF[base + 0] + eB[base + 0] + eb0;
    float s1 = start_t[1] + eF[base + 1] + eB[base + 1] + eb1;
    float s2 = start_t[2] + eF[base + 2] + eB[base + 2] + eb2;

    unsigned hist[LL - 1];
    unsigned maskbits = 0;

    #pragma unroll
    for (int l = 1; l < LL; ++l) {
        bool m = x[(b * LL + l) * WW + 2] > 0;
        if (m) maskbits |= (1u << l);
        int idx = base + l * TT;
        float e0 = eF[idx + 0] + eB[idx + 0] + eb0;
        float e1 = eF[idx + 1] + eB[idx + 1] + eb1;
        float e2 = eF[idx + 2] + eB[idx + 2] + eb2;

        float ns[3]; int pt[3];
        #pragma unroll
        for (int nt = 0; nt < 3; ++nt) {
            float c0 = s0 + tr[0 * 3 + nt];
            float c1 = s1 + tr[1 * 3 + nt];
            float c2 = s2 + tr[2 * 3 + nt];
            int p = 0; float bc = c0;
            if (c1 > bc) { bc = c1; p = 1; }   // strict '>': first-index argmax
            if (c2 > bc) { bc = c2; p = 2; }
            ns[nt] = bc; pt[nt] = p;
        }
        ns[0] += e0; ns[1] += e1; ns[2] += e2;
        hist[l - 1] = (unsigned)pt[0] | ((unsigned)pt[1] << 2) | ((unsigned)pt[2] << 4);
        if (m) { s0 = ns[0]; s1 = ns[1]; s2 = ns[2]; }
    }
    s0 += end_t[0]; s1 += end_t[1]; s2 += end_t[2];
    float best = s0; int last = 0;
    if (s1 > best) { best = s1; last = 1; }
    if (s2 > best) { best = s2; last = 2; }

    out[b] = best;
    float* tags = out + BB + b * LL;
    int tag = last;
    tags[LL - 1] = (float)last;
    #pragma unroll
    for (int l = LL - 1; l >= 1; --l) {
        int prev = (int)((hist[l - 1] >> (2 * tag)) & 3u);
        if (maskbits & (1u << l)) tag = prev;
        tags[l - 1] = (float)tag;
    }
}

// ---------------------------------------------------------------------------
extern "C" void kernel_launch(void* const* d_in, const int* in_sizes, int n_in,
                              void* d_out, int out_size, void* d_ws, size_t ws_size,
                              hipStream_t stream)
{
    const int*   x      = (const int*)  d_in[0];
    const float* emb    = (const float*)d_in[1];
    const float* conv_w = (const float*)d_in[2];
    const float* conv_b = (const float*)d_in[3];
    const float* bn1_g  = (const float*)d_in[4];
    const float* bn1_b  = (const float*)d_in[5];
    const float* bn1_m  = (const float*)d_in[6];
    const float* bn1_v  = (const float*)d_in[7];
    const float* w_ih_f = (const float*)d_in[8];
    const float* w_hh_f = (const float*)d_in[9];
    const float* b_f    = (const float*)d_in[10];
    const float* w_ih_b = (const float*)d_in[11];
    const float* w_hh_b = (const float*)d_in[12];
    const float* b_b    = (const float*)d_in[13];
    const float* bn2_g  = (const float*)d_in[14];
    const float* bn2_b  = (const float*)d_in[15];
    const float* bn2_m  = (const float*)d_in[16];
    const float* bn2_v  = (const float*)d_in[17];
    const float* fc_w   = (const float*)d_in[18];
    const float* fc_b   = (const float*)d_in[19];
    const float* trans  = (const float*)d_in[20];
    const float* start_t= (const float*)d_in[21];
    const float* end_t  = (const float*)d_in[22];

    float* ws  = (float*)d_ws;
    float* out = (float*)d_out;

    prep_kernel<<<256, 256, 0, stream>>>(emb, conv_w, conv_b,
                                         bn1_g, bn1_b, bn1_m, bn1_v,
                                         w_ih_f, w_hh_f, b_f,
                                         w_ih_b, w_hh_b, b_b,
                                         bn2_g, bn2_b, bn2_m, bn2_v,
                                         fc_w, fc_b, ws);
    lstm_kernel<<<256, 512, 0, stream>>>(x, ws);
    viterbi_kernel<<<16, 256, 0, stream>>>(x, ws, trans, start_t, end_t, out);
}

// Round 6
// 1255.636 us; speedup vs baseline: 1.3944x; 1.0091x over previous
//
#include <hip/hip_runtime.h>
#include <math.h>

// Problem constants
#define BB    4096   // batch
#define LL    30     // seq len
#define WW    5      // window
#define CC    40     // conv channels
#define HH    128    // lstm units
#define TT    3      // crf tags
#define KA    328    // 200 (features) + 128 (h)
#define NB    32     // batch rows per LSTM block

// Workspace layout (in floats)
#define WS_P    0                         // P'[3][30][40] conv collapsed + bn1 folded
#define WS_BC   3600                      // biasC[40]
#define WS_BG   3648                      // biasG[2][512]
#define WS_WFC  4672                      // Wfc[2][3][128]  (fc folded with bn2)
#define WS_EB   5440                      // ebias[3]
#define WS_WT   5504                      // Wt[2][328][128][4]  [k][unit][gate i,f,g,o]
#define WS_EMIS (5504 + 2*328*512)        // emis[2][B][L][3] partial emissions

typedef float v2f __attribute__((ext_vector_type(2)));

__device__ __forceinline__ float sigm(float x) {
    return __builtin_amdgcn_rcpf(1.0f + __expf(-x));
}
__device__ __forceinline__ float tanh_fast(float x) {
    return 2.0f * __builtin_amdgcn_rcpf(1.0f + __expf(-2.0f * x)) - 1.0f;
}

// ---------------------------------------------------------------------------
// Kernel 1: fold BN1 into conv tables, repack LSTM weights, fold BN2 into FC
// ---------------------------------------------------------------------------
__global__ void prep_kernel(const float* __restrict__ emb, const float* __restrict__ conv_w,
                            const float* __restrict__ conv_b,
                            const float* __restrict__ bn1_g, const float* __restrict__ bn1_b,
                            const float* __restrict__ bn1_m, const float* __restrict__ bn1_v,
                            const float* __restrict__ w_ih_f, const float* __restrict__ w_hh_f,
                            const float* __restrict__ b_f,
                            const float* __restrict__ w_ih_b, const float* __restrict__ w_hh_b,
                            const float* __restrict__ b_b,
                            const float* __restrict__ bn2_g, const float* __restrict__ bn2_b,
                            const float* __restrict__ bn2_m, const float* __restrict__ bn2_v,
                            const float* __restrict__ fc_w, const float* __restrict__ fc_b,
                            float* __restrict__ ws)
{
    const int gid = blockIdx.x * blockDim.x + threadIdx.x;
    const int gsz = gridDim.x * blockDim.x;

    // P'[k][a][c] = s1[c] * sum_e emb[a,e] * conv_w[c,e,k]
    for (int idx = gid; idx < 3600; idx += gsz) {
        int k = idx / 1200, rem = idx % 1200, a = rem / 40, c = rem % 40;
        float s1 = bn1_g[c] / sqrtf(bn1_v[c] + 1e-5f);
        float acc = 0.f;
        for (int e = 0; e < 128; ++e)
            acc += emb[a * 128 + e] * conv_w[(c * 128 + e) * 3 + k];
        ws[WS_P + idx] = acc * s1;
    }
    for (int c = gid; c < CC; c += gsz) {
        float s1 = bn1_g[c] / sqrtf(bn1_v[c] + 1e-5f);
        ws[WS_BC + c] = (conv_b[c] - bn1_m[c]) * s1 + bn1_b[c];
    }
    for (int i = gid; i < 1024; i += gsz) {
        int d = i >> 9, g = i & 511;
        ws[WS_BG + i] = d ? b_b[g] : b_f[g];
    }
    for (int i = gid; i < 768; i += gsz) {
        int d = i / 384, r = i % 384, t = r / 128, u = r % 128;
        int j = d * 128 + u;
        float s2 = bn2_g[j] / sqrtf(bn2_v[j] + 1e-5f);
        ws[WS_WFC + i] = fc_w[t * 256 + j] * s2;
    }
    for (int t = gid; t < TT; t += gsz) {
        float acc = fc_b[t];
        for (int j = 0; j < 256; ++j) {
            float s2 = bn2_g[j] / sqrtf(bn2_v[j] + 1e-5f);
            acc += fc_w[t * 256 + j] * (bn2_b[j] - bn2_m[j] * s2);
        }
        ws[WS_EB + t] = acc;
    }
    // Wt[d][k][u][g]: gate-quad contiguous per (k,unit) -> one dwordx4 per thread.
    for (int i = gid; i < 2 * KA * 512; i += gsz) {
        int d = i / (KA * 512), r = i % (KA * 512);
        int k = r / 512, j = r % 512, u = j >> 2, g = j & 3;
        int row = g * 128 + u;
        const float* wih = d ? w_ih_b : w_ih_f;
        const float* whh = d ? w_hh_b : w_hh_f;
        ws[WS_WT + i] = (k < 200) ? wih[row * 200 + k] : whh[row * 128 + (k - 200)];
    }
}

// ---------------------------------------------------------------------------
// Kernel 2: fused features + BiLSTM + partial emissions.
// 256 blocks = 2 dirs x 128 tiles of NB=32; 512 threads = 8 waves =
// (4 row-quarters of 8) x (2 unit-halves of 64), 2 waves/SIMD.
// GEMM uses v_pk_fma_f32 (fp32 packed, 2 FMA/inst — required for the
// 157 TF fp32 path): acc pairs (i,f) and (g,o) packed, a-value splat.
// kb-loop unrolled by 2 with alternating buffers (no v_mov double-buffer).
// ---------------------------------------------------------------------------
__global__ __launch_bounds__(512, 1)
void lstm_kernel(const int* __restrict__ x, float* __restrict__ ws)
{
    __shared__ float A[NB][336];         // [features(200) | h(128) | pad]
    __shared__ float Pp_s[3600];
    __shared__ float Wfc_s[384];
    __shared__ float biasC_s[40];

    const int tid = threadIdx.x;
    const int d   = blockIdx.x & 1;
    const int b0  = (blockIdx.x >> 1) * NB;

    const float4* __restrict__ Wg = (const float4*)(ws + WS_WT + d * (KA * 512));
    float* emis = ws + WS_EMIS + d * (BB * LL * TT);

    for (int i = tid; i < 3600; i += 512) Pp_s[i] = ws[WS_P + i];
    for (int i = tid; i < 384;  i += 512) Wfc_s[i] = ws[WS_WFC + d * 384 + i];
    for (int i = tid; i < 40;   i += 512) biasC_s[i] = ws[WS_BC + i];
    for (int i = tid; i < NB * HH; i += 512) A[i >> 7][200 + (i & 127)] = 0.f;

    const int lane = tid & 63;
    const int wv   = tid >> 6;          // 0..7
    const int uh   = wv & 1;            // unit half
    const int rb   = (wv >> 1) * 8;     // row base (4 quarters of 8)
    const int u    = uh * 64 + lane;    // this thread's unit

    const float* bgp = ws + WS_BG + d * 512;
    const float bI = bgp[u], bF = bgp[128 + u], bG = bgp[256 + u], bO = bgp[384 + u];

    v2f acc01[8], acc23[8];             // (i,f) and (g,o) packed pairs
    float cstv[8];
    #pragma unroll
    for (int r = 0; r < 8; ++r) cstv[r] = 0.f;

    __syncthreads();

    for (int step = 0; step < LL; ++step) {
        const int l = d ? (LL - 1 - step) : step;

        // ---- features: conv(table lookups) + bn1 + relu + maxpool -> A[:, :200]
        for (int p = tid; p < NB * CC; p += 512) {
            int bb = p / CC, c = p % CC;
            const int* tok = x + (((b0 + bb) * LL) + l) * WW;
            int t0 = tok[0], t1 = tok[1], t2 = tok[2], t3 = tok[3], t4 = tok[4];
            float bc = biasC_s[c];
            float a0 = bc + Pp_s[(30 + t0) * 40 + c] + Pp_s[(60 + t1) * 40 + c];
            float a1 = bc + Pp_s[t0 * 40 + c] + Pp_s[(30 + t1) * 40 + c] + Pp_s[(60 + t2) * 40 + c];
            float a2 = bc + Pp_s[t1 * 40 + c] + Pp_s[(30 + t2) * 40 + c] + Pp_s[(60 + t3) * 40 + c];
            float a3 = bc + Pp_s[t2 * 40 + c] + Pp_s[(30 + t3) * 40 + c] + Pp_s[(60 + t4) * 40 + c];
            float a4 = bc + Pp_s[t3 * 40 + c] + Pp_s[(30 + t4) * 40 + c];
            a0 = fmaxf(a0, 0.f); a1 = fmaxf(a1, 0.f); a2 = fmaxf(a2, 0.f);
            a3 = fmaxf(a3, 0.f); a4 = fmaxf(a4, 0.f);
            float* Af = &A[bb][c * 5];
            Af[0] = fmaxf(a0, a1);
            Af[1] = fmaxf(fmaxf(a0, a1), a2);
            Af[2] = fmaxf(fmaxf(a1, a2), a3);
            Af[3] = fmaxf(fmaxf(a2, a3), a4);
            Af[4] = fmaxf(a3, a4);
        }
        __syncthreads();   // features visible

        // ---- GEMM: acc[r][g] = sum_k A[rb+r][k] * Wt[k][u][g], k = 0..327 ----
        #pragma unroll
        for (int r = 0; r < 8; ++r) {
            acc01[r] = (v2f){0.f, 0.f};
            acc23[r] = (v2f){0.f, 0.f};
        }

#define KBODY(WB, K0)                                                          \
        {                                                                      \
            _Pragma("unroll")                                                  \
            for (int r = 0; r < 8; ++r) {                                      \
                float4 aA = *(const float4*)&A[rb + r][(K0)];                  \
                float4 aB = *(const float4*)&A[rb + r][(K0) + 4];              \
                float av[8] = {aA.x, aA.y, aA.z, aA.w, aB.x, aB.y, aB.z, aB.w};\
                _Pragma("unroll")                                              \
                for (int kk = 0; kk < 8; ++kk) {                               \
                    v2f a2 = {av[kk], av[kk]};                                 \
                    acc01[r] = __builtin_elementwise_fma(                      \
                        a2, (v2f){WB[kk].x, WB[kk].y}, acc01[r]);              \
                    acc23[r] = __builtin_elementwise_fma(                      \
                        a2, (v2f){WB[kk].z, WB[kk].w}, acc23[r]);              \
                }                                                              \
            }                                                                  \
        }

        float4 wb0[8], wb1[8];
        const float4* wpre = Wg + u;
        #pragma unroll
        for (int i = 0; i < 8; ++i) wb0[i] = wpre[i * 128];
        wpre += 1024;                   // -> kb 1

        for (int kb2 = 0; kb2 < 20; ++kb2) {
            // prefetch odd kb into wb1
            #pragma unroll
            for (int i = 0; i < 8; ++i) wb1[i] = wpre[i * 128];
            wpre += 1024;
            KBODY(wb0, kb2 * 16)
            // prefetch next even kb into wb0 (kb2*2+2 <= 40 always here)
            #pragma unroll
            for (int i = 0; i < 8; ++i) wb0[i] = wpre[i * 128];
            wpre += 1024;
            KBODY(wb1, kb2 * 16 + 8)
        }
        KBODY(wb0, 320)                 // kb = 40
#undef KBODY

        __syncthreads();   // all GEMM reads of h done before h overwrite

        // ---- gates (thread owns i,f,g,o of its unit) -> h into A[:,200+u] ----
        #pragma unroll
        for (int r = 0; r < 8; ++r) {
            float zi = acc01[r].x + bI;
            float zf = acc01[r].y + bF;
            float zg = acc23[r].x + bG;
            float zo = acc23[r].y + bO;
            float cn = sigm(zf) * cstv[r] + sigm(zi) * tanh_fast(zg);
            cstv[r] = cn;
            A[rb + r][200 + u] = sigm(zo) * tanh_fast(cn);
        }
        __syncthreads();   // h visible to emission readers + next step's GEMM

        // ---- partial emissions: 32 rows x 3 tags, split in 2 segments ----
        if (tid < 192) {
            int bb = tid / 6, r6 = tid % 6, t = r6 >> 1, seg = r6 & 1;
            const float* hv = &A[bb][200 + seg * 64];
            const float* wfc = &Wfc_s[t * 128 + seg * 64];
            float s = 0.f;
            #pragma unroll
            for (int i = 0; i < 16; ++i) {
                float4 ha = *(const float4*)(hv + i * 4);
                float4 wa = *(const float4*)(wfc + i * 4);
                s += ha.x * wa.x + ha.y * wa.y + ha.z * wa.z + ha.w * wa.w;
            }
            s += __shfl_xor(s, 1);
            if (seg == 0)
                emis[(((b0 + bb) * LL) + l) * TT + t] = s;
        }
        // next features phase writes A[:, :200] only; emission reads h region —
        // disjoint, no barrier needed here.
    }
}

// ---------------------------------------------------------------------------
// Kernel 3: Viterbi decode. One thread per batch row.
// ---------------------------------------------------------------------------
__global__ void viterbi_kernel(const int* __restrict__ x, const float* __restrict__ ws,
                               const float* __restrict__ trans,
                               const float* __restrict__ start_t,
                               const float* __restrict__ end_t,
                               float* __restrict__ out)
{
    int b = blockIdx.x * blockDim.x + threadIdx.x;
    if (b >= BB) return;
    const float* eF = ws + WS_EMIS;
    const float* eB = ws + WS_EMIS + BB * LL * TT;
    const float eb0 = ws[WS_EB + 0], eb1 = ws[WS_EB + 1], eb2 = ws[WS_EB + 2];
    float tr[9];
    #pragma unroll
    for (int i = 0; i < 9; ++i) tr[i] = trans[i];

    int base = b * LL * TT;
    float s0 = start_t[0] + eF[base + 0] + eB[base + 0] + eb0;
    float s1 = start_t[1] + eF[base + 1] + eB[base + 1] + eb1;
    float s2 = start_t[2] + eF[base + 2] + eB[base + 2] + eb2;

    unsigned hist[LL - 1];
    unsigned maskbits = 0;

    #pragma unroll
    for (int l = 1; l < LL; ++l) {
        bool m = x[(b * LL + l) * WW + 2] > 0;
        if (m) maskbits |= (1u << l);
        int idx = base + l * TT;
        float e0 = eF[idx + 0] + eB[idx + 0] + eb0;
        float e1 = eF[idx + 1] + eB[idx + 1] + eb1;
        float e2 = eF[idx + 2] + eB[idx + 2] + eb2;

        float ns[3]; int pt[3];
        #pragma unroll
        for (int nt = 0; nt < 3; ++nt) {
            float c0 = s0 + tr[0 * 3 + nt];
            float c1 = s1 + tr[1 * 3 + nt];
            float c2 = s2 + tr[2 * 3 + nt];
            int p = 0; float bc = c0;
            if (c1 > bc) { bc = c1; p = 1; }   // strict '>': first-index argmax
            if (c2 > bc) { bc = c2; p = 2; }
            ns[nt] = bc; pt[nt] = p;
        }
        ns[0] += e0; ns[1] += e1; ns[2] += e2;
        hist[l - 1] = (unsigned)pt[0] | ((unsigned)pt[1] << 2) | ((unsigned)pt[2] << 4);
        if (m) { s0 = ns[0]; s1 = ns[1]; s2 = ns[2]; }
    }
    s0 += end_t[0]; s1 += end_t[1]; s2 += end_t[2];
    float best = s0; int last = 0;
    if (s1 > best) { best = s1; last = 1; }
    if (s2 > best) { best = s2; last = 2; }

    out[b] = best;
    float* tags = out + BB + b * LL;
    int tag = last;
    tags[LL - 1] = (float)last;
    #pragma unroll
    for (int l = LL - 1; l >= 1; --l) {
        int prev = (int)((hist[l - 1] >> (2 * tag)) & 3u);
        if (maskbits & (1u << l)) tag = prev;
        tags[l - 1] = (float)tag;
    }
}

// ---------------------------------------------------------------------------
extern "C" void kernel_launch(void* const* d_in, const int* in_sizes, int n_in,
                              void* d_out, int out_size, void* d_ws, size_t ws_size,
                              hipStream_t stream)
{
    const int*   x      = (const int*)  d_in[0];
    const float* emb    = (const float*)d_in[1];
    const float* conv_w = (const float*)d_in[2];
    const float* conv_b = (const float*)d_in[3];
    const float* bn1_g  = (const float*)d_in[4];
    const float* bn1_b  = (const float*)d_in[5];
    const float* bn1_m  = (const float*)d_in[6];
    const float* bn1_v  = (const float*)d_in[7];
    const float* w_ih_f = (const float*)d_in[8];
    const float* w_hh_f = (const float*)d_in[9];
    const float* b_f    = (const float*)d_in[10];
    const float* w_ih_b = (const float*)d_in[11];
    const float* w_hh_b = (const float*)d_in[12];
    const float* b_b    = (const float*)d_in[13];
    const float* bn2_g  = (const float*)d_in[14];
    const float* bn2_b  = (const float*)d_in[15];
    const float* bn2_m  = (const float*)d_in[16];
    const float* bn2_v  = (const float*)d_in[17];
    const float* fc_w   = (const float*)d_in[18];
    const float* fc_b   = (const float*)d_in[19];
    const float* trans  = (const float*)d_in[20];
    const float* start_t= (const float*)d_in[21];
    const float* end_t  = (const float*)d_in[22];

    float* ws  = (float*)d_ws;
    float* out = (float*)d_out;

    prep_kernel<<<256, 256, 0, stream>>>(emb, conv_w, conv_b,
                                         bn1_g, bn1_b, bn1_m, bn1_v,
                                         w_ih_f, w_hh_f, b_f,
                                         w_ih_b, w_hh_b, b_b,
                                         bn2_g, bn2_b, bn2_m, bn2_v,
                                         fc_w, fc_b, ws);
    lstm_kernel<<<256, 512, 0, stream>>>(x, ws);
    viterbi_kernel<<<16, 256, 0, stream>>>(x, ws, trans, start_t, end_t, out);
}

// Round 7
// 1198.967 us; speedup vs baseline: 1.4603x; 1.0473x over previous
//
#include <hip/hip_runtime.h>
#include <math.h>

// Problem constants
#define BB    4096   // batch
#define LL    30     // seq len
#define WW    5      // window
#define CC    40     // conv channels
#define HH    128    // lstm units
#define TT    3      // crf tags
#define KA    328    // 200 (features) + 128 (h)
#define NB    32     // batch rows per LSTM block

// Workspace layout (in floats)
#define WS_P    0                         // P'[3][30][40] conv collapsed + bn1 folded
#define WS_BC   3600                      // biasC[40]
#define WS_BG   3648                      // biasG[2][512]
#define WS_WFC  4672                      // Wfc[2][3][128]  (fc folded with bn2)
#define WS_EB   5440                      // ebias[3]
#define WS_WT   5504                      // Wt[2][328][128][4]  [k][unit][gate i,f,g,o]
#define WS_EMIS (5504 + 2*328*512)        // emis[2][B][L][3] partial emissions

typedef float v2f __attribute__((ext_vector_type(2)));

__device__ __forceinline__ float sigm(float x) {
    return __builtin_amdgcn_rcpf(1.0f + __expf(-x));
}
__device__ __forceinline__ float tanh_fast(float x) {
    return 2.0f * __builtin_amdgcn_rcpf(1.0f + __expf(-2.0f * x)) - 1.0f;
}

// ---------------------------------------------------------------------------
// Kernel 1: fold BN1 into conv tables, repack LSTM weights, fold BN2 into FC
// ---------------------------------------------------------------------------
__global__ void prep_kernel(const float* __restrict__ emb, const float* __restrict__ conv_w,
                            const float* __restrict__ conv_b,
                            const float* __restrict__ bn1_g, const float* __restrict__ bn1_b,
                            const float* __restrict__ bn1_m, const float* __restrict__ bn1_v,
                            const float* __restrict__ w_ih_f, const float* __restrict__ w_hh_f,
                            const float* __restrict__ b_f,
                            const float* __restrict__ w_ih_b, const float* __restrict__ w_hh_b,
                            const float* __restrict__ b_b,
                            const float* __restrict__ bn2_g, const float* __restrict__ bn2_b,
                            const float* __restrict__ bn2_m, const float* __restrict__ bn2_v,
                            const float* __restrict__ fc_w, const float* __restrict__ fc_b,
                            float* __restrict__ ws)
{
    const int gid = blockIdx.x * blockDim.x + threadIdx.x;
    const int gsz = gridDim.x * blockDim.x;

    // P'[k][a][c] = s1[c] * sum_e emb[a,e] * conv_w[c,e,k]
    for (int idx = gid; idx < 3600; idx += gsz) {
        int k = idx / 1200, rem = idx % 1200, a = rem / 40, c = rem % 40;
        float s1 = bn1_g[c] / sqrtf(bn1_v[c] + 1e-5f);
        float acc = 0.f;
        for (int e = 0; e < 128; ++e)
            acc += emb[a * 128 + e] * conv_w[(c * 128 + e) * 3 + k];
        ws[WS_P + idx] = acc * s1;
    }
    for (int c = gid; c < CC; c += gsz) {
        float s1 = bn1_g[c] / sqrtf(bn1_v[c] + 1e-5f);
        ws[WS_BC + c] = (conv_b[c] - bn1_m[c]) * s1 + bn1_b[c];
    }
    for (int i = gid; i < 1024; i += gsz) {
        int d = i >> 9, g = i & 511;
        ws[WS_BG + i] = d ? b_b[g] : b_f[g];
    }
    for (int i = gid; i < 768; i += gsz) {
        int d = i / 384, r = i % 384, t = r / 128, u = r % 128;
        int j = d * 128 + u;
        float s2 = bn2_g[j] / sqrtf(bn2_v[j] + 1e-5f);
        ws[WS_WFC + i] = fc_w[t * 256 + j] * s2;
    }
    for (int t = gid; t < TT; t += gsz) {
        float acc = fc_b[t];
        for (int j = 0; j < 256; ++j) {
            float s2 = bn2_g[j] / sqrtf(bn2_v[j] + 1e-5f);
            acc += fc_w[t * 256 + j] * (bn2_b[j] - bn2_m[j] * s2);
        }
        ws[WS_EB + t] = acc;
    }
    // Wt[d][k][u][g]: gate-quad contiguous per (k,unit) -> one dwordx4 per thread.
    for (int i = gid; i < 2 * KA * 512; i += gsz) {
        int d = i / (KA * 512), r = i % (KA * 512);
        int k = r / 512, j = r % 512, u = j >> 2, g = j & 3;
        int row = g * 128 + u;
        const float* wih = d ? w_ih_b : w_ih_f;
        const float* whh = d ? w_hh_b : w_hh_f;
        ws[WS_WT + i] = (k < 200) ? wih[row * 200 + k] : whh[row * 128 + (k - 200)];
    }
}

// ---------------------------------------------------------------------------
// Kernel 2: fused features + BiLSTM + partial emissions.
// 256 blocks = 2 dirs x 128 tiles of NB=32; 512 threads = 8 waves =
// (4 row-quarters of 8) x (2 unit-halves of 64), 2 waves/SIMD (TLP is capped
// by the LDS/VMEM traffic balance — see R6 post-mortem). This round:
// intra-wave ILP — the LDS a-reads are software-pipelined with rolling 4-k
// register buffers so lgkm waits overlap the pk-FMA stream; W stays 1-kb
// ahead in wb0/wb1.
// ---------------------------------------------------------------------------
__global__ __launch_bounds__(512, 1)
void lstm_kernel(const int* __restrict__ x, float* __restrict__ ws)
{
    __shared__ float A[NB][336];         // [features(200) | h(128) | pad]
    __shared__ float Pp_s[3600];
    __shared__ float Wfc_s[384];
    __shared__ float biasC_s[40];

    const int tid = threadIdx.x;
    const int d   = blockIdx.x & 1;
    const int b0  = (blockIdx.x >> 1) * NB;

    const float4* __restrict__ Wg = (const float4*)(ws + WS_WT + d * (KA * 512));
    float* emis = ws + WS_EMIS + d * (BB * LL * TT);

    for (int i = tid; i < 3600; i += 512) Pp_s[i] = ws[WS_P + i];
    for (int i = tid; i < 384;  i += 512) Wfc_s[i] = ws[WS_WFC + d * 384 + i];
    for (int i = tid; i < 40;   i += 512) biasC_s[i] = ws[WS_BC + i];
    for (int i = tid; i < NB * HH; i += 512) A[i >> 7][200 + (i & 127)] = 0.f;

    const int lane = tid & 63;
    const int wv   = tid >> 6;          // 0..7
    const int uh   = wv & 1;            // unit half
    const int rb   = (wv >> 1) * 8;     // row base (4 quarters of 8)
    const int u    = uh * 64 + lane;    // this thread's unit

    const float* bgp = ws + WS_BG + d * 512;
    const float bI = bgp[u], bF = bgp[128 + u], bG = bgp[256 + u], bO = bgp[384 + u];

    v2f acc01[8], acc23[8];             // (i,f) and (g,o) packed pairs
    float cstv[8];
    #pragma unroll
    for (int r = 0; r < 8; ++r) cstv[r] = 0.f;

    __syncthreads();

    for (int step = 0; step < LL; ++step) {
        const int l = d ? (LL - 1 - step) : step;

        // ---- features: conv(table lookups) + bn1 + relu + maxpool -> A[:, :200]
        for (int p = tid; p < NB * CC; p += 512) {
            int bb = p / CC, c = p % CC;
            const int* tok = x + (((b0 + bb) * LL) + l) * WW;
            int t0 = tok[0], t1 = tok[1], t2 = tok[2], t3 = tok[3], t4 = tok[4];
            float bc = biasC_s[c];
            float a0 = bc + Pp_s[(30 + t0) * 40 + c] + Pp_s[(60 + t1) * 40 + c];
            float a1 = bc + Pp_s[t0 * 40 + c] + Pp_s[(30 + t1) * 40 + c] + Pp_s[(60 + t2) * 40 + c];
            float a2 = bc + Pp_s[t1 * 40 + c] + Pp_s[(30 + t2) * 40 + c] + Pp_s[(60 + t3) * 40 + c];
            float a3 = bc + Pp_s[t2 * 40 + c] + Pp_s[(30 + t3) * 40 + c] + Pp_s[(60 + t4) * 40 + c];
            float a4 = bc + Pp_s[t3 * 40 + c] + Pp_s[(30 + t4) * 40 + c];
            a0 = fmaxf(a0, 0.f); a1 = fmaxf(a1, 0.f); a2 = fmaxf(a2, 0.f);
            a3 = fmaxf(a3, 0.f); a4 = fmaxf(a4, 0.f);
            float* Af = &A[bb][c * 5];
            Af[0] = fmaxf(a0, a1);
            Af[1] = fmaxf(fmaxf(a0, a1), a2);
            Af[2] = fmaxf(fmaxf(a1, a2), a3);
            Af[3] = fmaxf(fmaxf(a2, a3), a4);
            Af[4] = fmaxf(a3, a4);
        }
        __syncthreads();   // features visible

        // ---- GEMM: acc[r][g] = sum_k A[rb+r][k] * Wt[k][u][g], k = 0..327 ----
        #pragma unroll
        for (int r = 0; r < 8; ++r) {
            acc01[r] = (v2f){0.f, 0.f};
            acc23[r] = (v2f){0.f, 0.f};
        }

        // FMA over 4 k-values held in register float4 buffer AQ (8 rows)
#define HFMA(WB, WOFF, AQ)                                                     \
        {                                                                      \
            _Pragma("unroll")                                                  \
            for (int r = 0; r < 8; ++r) {                                      \
                float av4[4] = {AQ[r].x, AQ[r].y, AQ[r].z, AQ[r].w};           \
                _Pragma("unroll")                                              \
                for (int kk = 0; kk < 4; ++kk) {                               \
                    v2f a2 = {av4[kk], av4[kk]};                               \
                    acc01[r] = __builtin_elementwise_fma(                      \
                        a2, (v2f){WB[(WOFF)+kk].x, WB[(WOFF)+kk].y}, acc01[r]);\
                    acc23[r] = __builtin_elementwise_fma(                      \
                        a2, (v2f){WB[(WOFF)+kk].z, WB[(WOFF)+kk].w}, acc23[r]);\
                }                                                              \
            }                                                                  \
        }
#define ALOAD(AQ, K0)                                                          \
        {                                                                      \
            _Pragma("unroll")                                                  \
            for (int r = 0; r < 8; ++r)                                        \
                AQ[r] = *(const float4*)&A[rb + r][(K0)];                      \
        }

        float4 wb0[8], wb1[8];          // W for even/odd kb (8 k each)
        float4 a_cur[8], a_nxt[8];      // rolling 4-k a-value buffers
        const float4* wpre = Wg + u;
        #pragma unroll
        for (int i = 0; i < 8; ++i) wb0[i] = wpre[i * 128];
        wpre += 1024;                   // -> kb 1
        ALOAD(a_cur, 0)

        for (int kb2 = 0; kb2 < 20; ++kb2) {
            const int kc = kb2 * 16;
            // prefetch odd kb's W into wb1
            #pragma unroll
            for (int i = 0; i < 8; ++i) wb1[i] = wpre[i * 128];
            wpre += 1024;
            ALOAD(a_nxt, kc + 4)        // a for second half of even kb
            HFMA(wb0, 0, a_cur)
            ALOAD(a_cur, kc + 8)        // a for first half of odd kb
            HFMA(wb0, 4, a_nxt)
            // prefetch next even kb's W into wb0 (kb2*2+2 <= 40 always here)
            #pragma unroll
            for (int i = 0; i < 8; ++i) wb0[i] = wpre[i * 128];
            wpre += 1024;
            ALOAD(a_nxt, kc + 12)       // second half of odd kb
            HFMA(wb1, 0, a_cur)
            ALOAD(a_cur, kc + 16)       // first half of next even kb (pad-safe at 336? kc+16<=320 ✓)
            HFMA(wb1, 4, a_nxt)
        }
        // kb = 40 (k = 320..327), W already in wb0, a_cur holds k=320..323
        ALOAD(a_nxt, 324)
        HFMA(wb0, 0, a_cur)
        HFMA(wb0, 4, a_nxt)
#undef HFMA
#undef ALOAD

        __syncthreads();   // all GEMM reads of h done before h overwrite

        // ---- gates (thread owns i,f,g,o of its unit) -> h into A[:,200+u] ----
        #pragma unroll
        for (int r = 0; r < 8; ++r) {
            float zi = acc01[r].x + bI;
            float zf = acc01[r].y + bF;
            float zg = acc23[r].x + bG;
            float zo = acc23[r].y + bO;
            float cn = sigm(zf) * cstv[r] + sigm(zi) * tanh_fast(zg);
            cstv[r] = cn;
            A[rb + r][200 + u] = sigm(zo) * tanh_fast(cn);
        }
        __syncthreads();   // h visible to emission readers + next step's GEMM

        // ---- partial emissions: 32 rows x 3 tags, split in 2 segments ----
        if (tid < 192) {
            int bb = tid / 6, r6 = tid % 6, t = r6 >> 1, seg = r6 & 1;
            const float* hv = &A[bb][200 + seg * 64];
            const float* wfc = &Wfc_s[t * 128 + seg * 64];
            float s = 0.f;
            #pragma unroll
            for (int i = 0; i < 16; ++i) {
                float4 ha = *(const float4*)(hv + i * 4);
                float4 wa = *(const float4*)(wfc + i * 4);
                s += ha.x * wa.x + ha.y * wa.y + ha.z * wa.z + ha.w * wa.w;
            }
            s += __shfl_xor(s, 1);
            if (seg == 0)
                emis[(((b0 + bb) * LL) + l) * TT + t] = s;
        }
        // next features phase writes A[:, :200] only; emission reads h region —
        // disjoint, no barrier needed here.
    }
}

// ---------------------------------------------------------------------------
// Kernel 3: Viterbi decode. One thread per batch row.
// ---------------------------------------------------------------------------
__global__ void viterbi_kernel(const int* __restrict__ x, const float* __restrict__ ws,
                               const float* __restrict__ trans,
                               const float* __restrict__ start_t,
                               const float* __restrict__ end_t,
                               float* __restrict__ out)
{
    int b = blockIdx.x * blockDim.x + threadIdx.x;
    if (b >= BB) return;
    const float* eF = ws + WS_EMIS;
    const float* eB = ws + WS_EMIS + BB * LL * TT;
    const float eb0 = ws[WS_EB + 0], eb1 = ws[WS_EB + 1], eb2 = ws[WS_EB + 2];
    float tr[9];
    #pragma unroll
    for (int i = 0; i < 9; ++i) tr[i] = trans[i];

    int base = b * LL * TT;
    float s0 = start_t[0] + eF[base + 0] + eB[base + 0] + eb0;
    float s1 = start_t[1] + eF[base + 1] + eB[base + 1] + eb1;
    float s2 = start_t[2] + eF[base + 2] + eB[base + 2] + eb2;

    unsigned hist[LL - 1];
    unsigned maskbits = 0;

    #pragma unroll
    for (int l = 1; l < LL; ++l) {
        bool m = x[(b * LL + l) * WW + 2] > 0;
        if (m) maskbits |= (1u << l);
        int idx = base + l * TT;
        float e0 = eF[idx + 0] + eB[idx + 0] + eb0;
        float e1 = eF[idx + 1] + eB[idx + 1] + eb1;
        float e2 = eF[idx + 2] + eB[idx + 2] + eb2;

        float ns[3]; int pt[3];
        #pragma unroll
        for (int nt = 0; nt < 3; ++nt) {
            float c0 = s0 + tr[0 * 3 + nt];
            float c1 = s1 + tr[1 * 3 + nt];
            float c2 = s2 + tr[2 * 3 + nt];
            int p = 0; float bc = c0;
            if (c1 > bc) { bc = c1; p = 1; }   // strict '>': first-index argmax
            if (c2 > bc) { bc = c2; p = 2; }
            ns[nt] = bc; pt[nt] = p;
        }
        ns[0] += e0; ns[1] += e1; ns[2] += e2;
        hist[l - 1] = (unsigned)pt[0] | ((unsigned)pt[1] << 2) | ((unsigned)pt[2] << 4);
        if (m) { s0 = ns[0]; s1 = ns[1]; s2 = ns[2]; }
    }
    s0 += end_t[0]; s1 += end_t[1]; s2 += end_t[2];
    float best = s0; int last = 0;
    if (s1 > best) { best = s1; last = 1; }
    if (s2 > best) { best = s2; last = 2; }

    out[b] = best;
    float* tags = out + BB + b * LL;
    int tag = last;
    tags[LL - 1] = (float)last;
    #pragma unroll
    for (int l = LL - 1; l >= 1; --l) {
        int prev = (int)((hist[l - 1] >> (2 * tag)) & 3u);
        if (maskbits & (1u << l)) tag = prev;
        tags[l - 1] = (float)tag;
    }
}

// ---------------------------------------------------------------------------
extern "C" void kernel_launch(void* const* d_in, const int* in_sizes, int n_in,
                              void* d_out, int out_size, void* d_ws, size_t ws_size,
                              hipStream_t stream)
{
    const int*   x      = (const int*)  d_in[0];
    const float* emb    = (const float*)d_in[1];
    const float* conv_w = (const float*)d_in[2];
    const float* conv_b = (const float*)d_in[3];
    const float* bn1_g  = (const float*)d_in[4];
    const float* bn1_b  = (const float*)d_in[5];
    const float* bn1_m  = (const float*)d_in[6];
    const float* bn1_v  = (const float*)d_in[7];
    const float* w_ih_f = (const float*)d_in[8];
    const float* w_hh_f = (const float*)d_in[9];
    const float* b_f    = (const float*)d_in[10];
    const float* w_ih_b = (const float*)d_in[11];
    const float* w_hh_b = (const float*)d_in[12];
    const float* b_b    = (const float*)d_in[13];
    const float* bn2_g  = (const float*)d_in[14];
    const float* bn2_b  = (const float*)d_in[15];
    const float* bn2_m  = (const float*)d_in[16];
    const float* bn2_v  = (const float*)d_in[17];
    const float* fc_w   = (const float*)d_in[18];
    const float* fc_b   = (const float*)d_in[19];
    const float* trans  = (const float*)d_in[20];
    const float* start_t= (const float*)d_in[21];
    const float* end_t  = (const float*)d_in[22];

    float* ws  = (float*)d_ws;
    float* out = (float*)d_out;

    prep_kernel<<<256, 256, 0, stream>>>(emb, conv_w, conv_b,
                                         bn1_g, bn1_b, bn1_m, bn1_v,
                                         w_ih_f, w_hh_f, b_f,
                                         w_ih_b, w_hh_b, b_b,
                                         bn2_g, bn2_b, bn2_m, bn2_v,
                                         fc_w, fc_b, ws);
    lstm_kernel<<<256, 512, 0, stream>>>(x, ws);
    viterbi_kernel<<<16, 256, 0, stream>>>(x, ws, trans, start_t, end_t, out);
}